// Round 13
// baseline (267.538 us; speedup 1.0000x reference)
//
#include <hip/hip_runtime.h>
#include <math.h>

#define NN 4096
#define DD 512
#define FF 512
#define CAP 256
#define SCALE 0.08838834764831845f

typedef unsigned short u16;
typedef unsigned char u8;
typedef unsigned int u32;
typedef __attribute__((ext_vector_type(8))) short short8;
typedef __attribute__((ext_vector_type(8))) unsigned short ushort8;
typedef __attribute__((ext_vector_type(4))) unsigned short ushort4v;
typedef __attribute__((ext_vector_type(4))) float floatx4;
typedef __attribute__((ext_vector_type(2))) float f32x2;
typedef _Float16 half8v __attribute__((ext_vector_type(8)));

__device__ __forceinline__ u16 f2bf(float f) {
    union { float f; unsigned int i; } x; x.f = f;
    unsigned int r = (x.i + 0x7FFFu + ((x.i >> 16) & 1u)) >> 16;
    return (u16)r;
}
__device__ __forceinline__ u16 f2h(float f) {
    _Float16 h = (_Float16)f;
    union { _Float16 h; u16 u; } x; x.h = h; return x.u;
}
// f32 -> fp8 e4m3 (RNE) via the f16 domain: e4m3 bits == f16 bits of (x/256) >> 7.
__device__ __forceinline__ u8 f2fp8(float f) {
    union { _Float16 h; u16 u; } x;
    x.h = (_Float16)(f * 0.00390625f);          // /256
    u16 h = x.u;
    h = h + 0x3F + ((h >> 7) & 1);              // RNE on the 7 dropped bits
    return (u8)(((h >> 8) & 0x80) | ((h >> 7) & 0x7f));
}
__device__ __forceinline__ float fp82f_sw(u8 b) {
    union { u16 u; _Float16 h; } x;
    x.u = (u16)(((u16)(b & 0x80) << 8) | ((u16)(b & 0x7f) << 7));
    return (float)x.h * 256.0f;
}
__device__ __forceinline__ void gld_lds16(const void* g, void* l) {
    __builtin_amdgcn_global_load_lds((const __attribute__((address_space(1))) void*)g,
                                     (__attribute__((address_space(3))) void*)l, 16, 0, 0);
}

// fast exact-gelu: A&S 7.1.26 erf approx, |eps_erf| <= 1.5e-7
__device__ __forceinline__ float gelu_fast(float val) {
    float z = fabsf(val) * 0.70710678118654752f;
    float tt = __builtin_amdgcn_rcpf(fmaf(0.3275911f, z, 1.0f));
    float p = fmaf(1.061405429f, tt, -1.453152027f);
    p = fmaf(p, tt, 1.421413741f);
    p = fmaf(p, tt, -0.284496736f);
    p = fmaf(p, tt, 0.254829592f);
    p = p * tt * __expf(-z * z);
    float er_ = 1.0f - p;
    float sgn = (val < 0.f) ? -er_ : er_;
    return val * 0.5f * (1.0f + sgn);
}

// ---------------------------------------------------------------- fused setup (R8-proven)
// [0,192): weight cast fp32->bf16 with LN-gamma fold; blocks 2,3 also zero st1..st3
// [192, 192+NN): mask -> idx  +  nfeat stats -> st0  +  nfeat -> xb (bf16), one row per block
// [192+NN, +1024): c1/c2 fold, one column per wave
struct SP {
    const float* w[6];
    const float* bq; const float* bk; const float* bv; const float* fc1_b;
    const float* ln1_g; const float* ln1_b; const float* ln2_g; const float* ln2_b;
    const float* nfeat; const int* mask;
};
__global__ void setup_kernel(SP sp, u16* __restrict__ wc, float* __restrict__ bc2,
                             float* __restrict__ c1c, float* __restrict__ st,
                             u16* __restrict__ xb, int* __restrict__ idx,
                             int* __restrict__ cnt) {
    const int bid = blockIdx.x;
    const int t = threadIdx.x;
    const int wave = t >> 6, lane = t & 63;
    if (bid < 192) {
        // ---- weight cast with gamma fold ----
        int region = bid >> 4;
        int layer = region / 6, mat = region - layer * 6;
        const float* src = sp.w[mat] + (size_t)layer * (DD * DD);
        u16* d = wc + (size_t)region * (DD * DD);
        int off = (bid & 15) * 16384 + t * 4;
        int k = (t * 4) & 511;
        float4 g4 = {1.f, 1.f, 1.f, 1.f};
        if (mat < 3)      g4 = *(const float4*)&sp.ln1_g[layer * DD + k];
        else if (mat == 4) g4 = *(const float4*)&sp.ln2_g[layer * DD + k];
#pragma unroll
        for (int i = 0; i < 16; i++) {
            int e = off + i * 1024;
            float4 f = *(const float4*)&src[e];
            ushort4v u;
            u.x = f2bf(f.x * g4.x); u.y = f2bf(f.y * g4.y);
            u.z = f2bf(f.z * g4.z); u.w = f2bf(f.w * g4.w);
            *(ushort4v*)&d[e] = u;
        }
        if (bid == 2 || bid == 3) {   // zero st1..st3 (atomic accumulators)
            float* z = st + 8192;
            int base = (bid - 2) * 256 + t;
#pragma unroll
            for (int i = 0; i < 48; i++) z[base + i * 512] = 0.0f;
        }
        return;
    }
    if (bid < 192 + NN) {
        int row = bid - 192;
        // ---- nfeat: stats + bf16 cast (2 elems/thread) ----
        __shared__ int c;
        __shared__ float ws[4][2];
        const float* xr = sp.nfeat + (size_t)row * DD;
        float2 v2 = *(const float2*)&xr[t * 2];
        float s1 = v2.x + v2.y, s2 = v2.x * v2.x + v2.y * v2.y;
#pragma unroll
        for (int off = 32; off; off >>= 1) { s1 += __shfl_xor(s1, off); s2 += __shfl_xor(s2, off); }
        if (lane == 0) { ws[wave][0] = s1; ws[wave][1] = s2; }
        u32 pack = (u32)f2bf(v2.x) | ((u32)f2bf(v2.y) << 16);
        ((u32*)xb)[row * 256 + t] = pack;
        if (t == 0) c = 0;
        __syncthreads();
        if (t == 0) {
            float S1 = ws[0][0] + ws[1][0] + ws[2][0] + ws[3][0];
            float S2 = ws[0][1] + ws[1][1] + ws[2][1] + ws[3][1];
            st[row * 2] = S1; st[row * 2 + 1] = S2;
        }
        // ---- mask -> idx (block-per-row, LDS atomic; R0-proven shape) ----
        const int4* mrow = (const int4*)(sp.mask + (size_t)row * NN);
        for (int j4 = t; j4 < NN / 4; j4 += blockDim.x) {
            int4 m4 = mrow[j4];
            int base = j4 * 4;
            if (m4.x == 0) idx[row * CAP + atomicAdd(&c, 1)] = base;
            if (m4.y == 0) idx[row * CAP + atomicAdd(&c, 1)] = base + 1;
            if (m4.z == 0) idx[row * CAP + atomicAdd(&c, 1)] = base + 2;
            if (m4.w == 0) idx[row * CAP + atomicAdd(&c, 1)] = base + 3;
        }
        __syncthreads();
        if (t == 0) cnt[row] = (c < CAP) ? c : CAP;
        return;
    }
    // ---- c1/c2 fold: one column per wave (R8-proven) ----
    {
        int colg = (bid - (192 + NN)) * 4 + wave;   // 0..4095
        int l = colg >> 11, j = colg & 2047;
        const float* W; const float* g; const float* b; float bias;
        if (j < 1536) {
            int mat = j >> 9, col = j & 511;
            W = sp.w[mat] + (size_t)l * DD * DD + (size_t)col * DD;
            g = sp.ln1_g + l * DD; b = sp.ln1_b + l * DD;
            bias = (mat == 0 ? sp.bq : mat == 1 ? sp.bk : sp.bv)[l * DD + col];
        } else {
            int col = j - 1536;
            W = sp.w[4] + (size_t)l * DD * DD + (size_t)col * DD;
            g = sp.ln2_g + l * DD; b = sp.ln2_b + l * DD;
            bias = sp.fc1_b[l * DD + col];
        }
        int k = lane * 8;
        float4 w0 = *(const float4*)&W[k];
        float4 w1 = *(const float4*)&W[k + 4];
        float4 g0 = *(const float4*)&g[k];
        float4 g1 = *(const float4*)&g[k + 4];
        float4 b0 = *(const float4*)&b[k];
        float4 b1 = *(const float4*)&b[k + 4];
        float c1 = w0.x * g0.x + w0.y * g0.y + w0.z * g0.z + w0.w * g0.w
                 + w1.x * g1.x + w1.y * g1.y + w1.z * g1.z + w1.w * g1.w;
        float c2 = w0.x * b0.x + w0.y * b0.y + w0.z * b0.z + w0.w * b0.w
                 + w1.x * b1.x + w1.y * b1.y + w1.z * b1.z + w1.w * b1.w;
#pragma unroll
        for (int off = 32; off; off >>= 1) { c1 += __shfl_xor(c1, off); c2 += __shfl_xor(c2, off); }
        if (lane == 0) { c1c[colg] = c1; bc2[colg] = bias + c2; }
    }
}

// LDS row-rotation swizzle (R12-proven): LDS(row, pos) holds global chunk (pos - row) & 7.

// ---------------------------------------------------------------- 64x64 FC GEMM (R0-proven body)
// XCD-aware tile swizzle (T1, R11-proven).
// LNF=1: A is raw-x bf16, B is gamma-folded; epilogue applies val = r*acc - r*mu*c1 + bc2
// MODE 1: gelu -> bf16 outB; MODE 2: resOut = resIn + val (+ optional xb shadow + row stats)
template <int MODE, int LNF>
__launch_bounds__(256)
__global__ void gemm_fc(const u16* __restrict__ A, const u16* __restrict__ B,
                        const float* __restrict__ bias, const float* __restrict__ c1,
                        const float* __restrict__ stats, const float* __restrict__ resIn,
                        float* __restrict__ resOut, u16* __restrict__ outB,
                        u16* __restrict__ xbOut, float* __restrict__ statsOut) {
    __shared__ __align__(16) u8 smem[16384];
    u16* As = (u16*)smem;
    u16* Bs = (u16*)(smem + 8192);
    const int lin = blockIdx.x + blockIdx.y * 8;        // 512 tiles, round-robin over 8 XCDs
    const int v = (lin & 7) * 64 + (lin >> 3);          // bijective: XCD-contiguous tile bands
    const int m0 = (v >> 3) * 64, n0 = (v & 7) * 64;
    const int t = threadIdx.x;
    const int wave = t >> 6, lane = t & 63;
    const int wm = (wave & 1) * 32, wn = (wave >> 1) * 32;
    const int sr = t >> 3;
    const int sc = ((((t & 7) - (t >> 3)) & 7)) * 8;
    const int fr = lane & 15, g0 = lane >> 4;
    const int er = (lane >> 4) * 4, ec = lane & 15;

    floatx4 acc[2][2] = {};
    const u16* ag0 = A + (size_t)(m0 + sr) * 512 + sc;
    const u16* ag1 = A + (size_t)(m0 + 32 + sr) * 512 + sc;
    const u16* bg0 = B + (size_t)(n0 + sr) * 512 + sc;
    const u16* bg1 = B + (size_t)(n0 + 32 + sr) * 512 + sc;

    float rin[16];
    if (MODE == 2) {
#pragma unroll
        for (int i = 0; i < 2; i++)
#pragma unroll
            for (int j = 0; j < 2; j++)
#pragma unroll
                for (int r = 0; r < 4; r++)
                    rin[(i * 2 + j) * 4 + r] =
                        resIn[(size_t)(m0 + wm + 16 * i + er + r) * 512 + (n0 + wn + 16 * j + ec)];
    }
    // LNF: per-row affine (a = r, b = -r*mu) for this thread's 8 rows
    float ar[2][4], br[2][4];
    if (LNF) {
#pragma unroll
        for (int i = 0; i < 2; i++) {
            int r0 = m0 + wm + 16 * i + er;
#pragma unroll
            for (int r = 0; r < 4; r++) {
                f32x2 s = *(const f32x2*)&stats[(r0 + r) * 2];
                float m = s.x * (1.0f / DD);
                float rr = rsqrtf(s.y * (1.0f / DD) - m * m + 1e-5f);
                ar[i][r] = rr; br[i][r] = -rr * m;
            }
        }
    }

    for (int k0 = 0; k0 < 512; k0 += 64) {
        __syncthreads();
        gld_lds16(ag0 + k0, As + t * 8);
        gld_lds16(ag1 + k0, As + 2048 + t * 8);
        gld_lds16(bg0 + k0, Bs + t * 8);
        gld_lds16(bg1 + k0, Bs + 2048 + t * 8);
        __syncthreads();
#pragma unroll
        for (int h = 0; h < 2; h++) {
            const int fo = (((h << 2) + g0 + fr) & 7) << 3;
            short8 af[2], bf[2];
#pragma unroll
            for (int i = 0; i < 2; i++) af[i] = *(const short8*)&As[(wm + 16 * i + fr) * 64 + fo];
#pragma unroll
            for (int j = 0; j < 2; j++) bf[j] = *(const short8*)&Bs[(wn + 16 * j + fr) * 64 + fo];
#pragma unroll
            for (int i = 0; i < 2; i++)
#pragma unroll
                for (int j = 0; j < 2; j++)
                    acc[i][j] = __builtin_amdgcn_mfma_f32_16x16x32_bf16(af[i], bf[j], acc[i][j], 0, 0, 0);
        }
    }

    float outv[16];
#pragma unroll
    for (int j = 0; j < 2; j++) {
        int col = n0 + wn + 16 * j + ec;
        float bsv = bias[col];
        float c1v = LNF ? c1[col] : 0.f;
#pragma unroll
        for (int i = 0; i < 2; i++) {
#pragma unroll
            for (int r = 0; r < 4; r++) {
                int row = m0 + wm + 16 * i + er + r;
                float val;
                if (LNF) val = fmaf(ar[i][r], acc[i][j][r], fmaf(br[i][r], c1v, bsv));
                else     val = acc[i][j][r] + bsv;
                if (MODE == 1) {
                    outB[(size_t)row * 512 + col] = f2bf(gelu_fast(val));
                } else {
                    float ov = rin[(i * 2 + j) * 4 + r] + val;
                    outv[(i * 2 + j) * 4 + r] = ov;
                    resOut[(size_t)row * 512 + col] = ov;
                    if (xbOut) xbOut[(size_t)row * 512 + col] = f2bf(ov);
                }
            }
        }
    }

    if (MODE == 2 && statsOut) {   // row (sum, sumsq) accumulation for the next LN (R2-proven)
        __syncthreads();
        float* Ls = (float*)smem;              // 64x64 f32 = 16 KB
#pragma unroll
        for (int i = 0; i < 2; i++)
#pragma unroll
            for (int j = 0; j < 2; j++)
#pragma unroll
                for (int r = 0; r < 4; r++)
                    Ls[(wm + 16 * i + er + r) * 64 + (wn + 16 * j + ec)] = outv[(i * 2 + j) * 4 + r];
        __syncthreads();
        if (t < 64) {
            float s1 = 0.f, s2 = 0.f;
            for (int c0 = 0; c0 < 64; c0++) {
                int cc = (c0 + t) & 63;        // stagger: 2-way conflict max (free)
                float v2 = Ls[t * 64 + cc];
                s1 += v2; s2 += v2 * v2;
            }
            atomicAdd(&statsOut[(size_t)(m0 + t) * 2], s1);
            atomicAdd(&statsOut[(size_t)(m0 + t) * 2 + 1], s2);
        }
    }
}

// ---------------------------------------------------------------- 128x64 QKV GEMM (R0-proven body)
// XCD-aware tile swizzle (T1). LN folded; epilogue applies per-row affine.
// Q -> f16 q[N,512]; K/V -> fp8 interleaved kv8[N][64 grp][K8|V8]
__launch_bounds__(256)
__global__ void gemm_qkv(const u16* __restrict__ A, const u16* __restrict__ B,
                         const float* __restrict__ bias, const float* __restrict__ c1,
                         const float* __restrict__ stats, u16* __restrict__ qOut,
                         u8* __restrict__ kv8) {
    __shared__ u16 As[128 * 64];   // 16 KB
    __shared__ u16 Bs[64 * 64];    // 8 KB
    const int lin = blockIdx.x + blockIdx.y * 24;       // 768 tiles
    const int v = (lin & 7) * 96 + (lin >> 3);          // bijective XCD bands
    const int rb = v / 24, cb = v - rb * 24;
    const int m0 = rb * 128, n0 = cb * 64;
    const int t = threadIdx.x;
    const int wave = t >> 6, lane = t & 63;
    const int wm = (wave & 1) * 64, wn = (wave >> 1) * 32;
    const int sr = t >> 3;
    const int sc = ((((t & 7) - (t >> 3)) & 7)) * 8;
    const int fr = lane & 15, g0 = lane >> 4;
    const int er = (lane >> 4) * 4, ec = lane & 15;

    floatx4 acc[4][2] = {};
    const u16* agp[4];
    u16* asp[4];
#pragma unroll
    for (int u = 0; u < 4; u++) {
        agp[u] = A + (size_t)(m0 + 32 * u + sr) * DD + sc;
        asp[u] = As + u * (32 * 64) + t * 8;
    }
    const u16* bg0 = B + (size_t)(n0 + sr) * DD + sc;
    const u16* bg1 = B + (size_t)(n0 + 32 + sr) * DD + sc;

    float ar[4][4], br[4][4];
#pragma unroll
    for (int i = 0; i < 4; i++) {
        int r0 = m0 + wm + 16 * i + er;
#pragma unroll
        for (int r = 0; r < 4; r++) {
            f32x2 s = *(const f32x2*)&stats[(r0 + r) * 2];
            float m = s.x * (1.0f / DD);
            float rr = rsqrtf(s.y * (1.0f / DD) - m * m + 1e-5f);
            ar[i][r] = rr; br[i][r] = -rr * m;
        }
    }

    for (int k0 = 0; k0 < DD; k0 += 64) {
        __syncthreads();
#pragma unroll
        for (int u = 0; u < 4; u++) gld_lds16(agp[u] + k0, asp[u]);
        gld_lds16(bg0 + k0, Bs + t * 8);
        gld_lds16(bg1 + k0, Bs + 2048 + t * 8);
        __syncthreads();
#pragma unroll
        for (int h = 0; h < 2; h++) {
            const int fo = (((h << 2) + g0 + fr) & 7) << 3;
            short8 af[4], bf[2];
#pragma unroll
            for (int i = 0; i < 4; i++) af[i] = *(const short8*)&As[(wm + 16 * i + fr) * 64 + fo];
#pragma unroll
            for (int j = 0; j < 2; j++) bf[j] = *(const short8*)&Bs[(wn + 16 * j + fr) * 64 + fo];
#pragma unroll
            for (int i = 0; i < 4; i++)
#pragma unroll
                for (int j = 0; j < 2; j++)
                    acc[i][j] = __builtin_amdgcn_mfma_f32_16x16x32_bf16(af[i], bf[j], acc[i][j], 0, 0, 0);
        }
    }

#pragma unroll
    for (int j = 0; j < 2; j++) {
        int col = n0 + wn + 16 * j + ec;
        float bsv = bias[col];
        float c1v = c1[col];
#pragma unroll
        for (int i = 0; i < 4; i++) {
#pragma unroll
            for (int r = 0; r < 4; r++) {
                int row = m0 + wm + 16 * i + er + r;
                float val = fmaf(ar[i][r], acc[i][j][r], fmaf(br[i][r], c1v, bsv));
                if (cb < 8) {                         // Q -> f16
                    qOut[(size_t)row * 512 + col] = f2h(val);
                } else if (cb < 16) {                 // K -> fp8, group-interleaved
                    int cc = col - 512;
                    kv8[(size_t)row * 1024 + 16 * (cc >> 3) + (cc & 7)] = f2fp8(val);
                } else {                              // V -> fp8
                    int cc = col - 1024;
                    kv8[(size_t)row * 1024 + 16 * (cc >> 3) + 8 + (cc & 7)] = f2fp8(val);
                }
            }
        }
    }
}

// ---------------------------------------------------------------- sparse attention v3 (R13):
// 8 waves/query, 1 query/block; serial key-chain ~5-6 iters (avg ~41 keys);
// fp8 KV, f16 Q; 2-iter prefetch (stride-8 lookahead j+16); 7-partial LDS combine.
__launch_bounds__(512)
__global__ void sparse_attn(const u16* __restrict__ q, const u8* __restrict__ kv8,
                            const int* __restrict__ idx, const int* __restrict__ cnt,
                            u16* __restrict__ o) {
    int t = threadIdx.x;
    int wave = t >> 6, lane = t & 63;
    int qi = blockIdx.x;
    __shared__ float obuf[7][64][8];   // 14 KB: partials from waves 1..7
    __shared__ float sbuf[7][64];      // 1.75 KB
    __shared__ int sidx[CAP];          // 1 KB

    int c = cnt[qi];
    for (int j = t; j < c; j += 512) sidx[j] = idx[qi * CAP + j];

    half8v qv = *(const half8v*)(q + (size_t)qi * 512 + lane * 8);
    float qf[8];
#pragma unroll
    for (int e = 0; e < 8; e++) qf[e] = (float)qv[e];
    __syncthreads();

    float sum = 0.f, oa[8] = {};
    int j = wave;
    int4 kv0, kv1;
    {
        int k0i = (j < c) ? sidx[j] : 0;
        int k1i = (j + 8 < c) ? sidx[j + 8] : 0;
        kv0 = *(const int4*)(kv8 + (size_t)k0i * 1024 + lane * 16);
        kv1 = *(const int4*)(kv8 + (size_t)k1i * 1024 + lane * 16);
    }
    while (j < c) {
        int4 kvn;
        {
            int kjn = (j + 16 < c) ? sidx[j + 16] : 0;
            kvn = *(const int4*)(kv8 + (size_t)kjn * 1024 + lane * 16);
        }
        float kd[8], vd[8];
#if __has_builtin(__builtin_amdgcn_cvt_pk_f32_fp8)
        {
            f32x2 p0 = __builtin_amdgcn_cvt_pk_f32_fp8(kv0.x, false);
            f32x2 p1 = __builtin_amdgcn_cvt_pk_f32_fp8(kv0.x, true);
            f32x2 p2 = __builtin_amdgcn_cvt_pk_f32_fp8(kv0.y, false);
            f32x2 p3 = __builtin_amdgcn_cvt_pk_f32_fp8(kv0.y, true);
            kd[0] = p0.x; kd[1] = p0.y; kd[2] = p1.x; kd[3] = p1.y;
            kd[4] = p2.x; kd[5] = p2.y; kd[6] = p3.x; kd[7] = p3.y;
            f32x2 p4 = __builtin_amdgcn_cvt_pk_f32_fp8(kv0.z, false);
            f32x2 p5 = __builtin_amdgcn_cvt_pk_f32_fp8(kv0.z, true);
            f32x2 p6 = __builtin_amdgcn_cvt_pk_f32_fp8(kv0.w, false);
            f32x2 p7 = __builtin_amdgcn_cvt_pk_f32_fp8(kv0.w, true);
            vd[0] = p4.x; vd[1] = p4.y; vd[2] = p5.x; vd[3] = p5.y;
            vd[4] = p6.x; vd[5] = p6.y; vd[6] = p7.x; vd[7] = p7.y;
        }
#else
        {
            const u8* bp = (const u8*)&kv0;
#pragma unroll
            for (int e = 0; e < 8; e++) { kd[e] = fp82f_sw(bp[e]); vd[e] = fp82f_sw(bp[8 + e]); }
        }
#endif
        float d = 0.f;
#pragma unroll
        for (int e = 0; e < 8; e++) d = fmaf(qf[e], kd[e], d);
        d += __shfl_xor(d, 1);
        d += __shfl_xor(d, 2);
        d += __shfl_xor(d, 4);
        d += __shfl_xor(d, 8);
        float p = __expf(d * SCALE);
        sum += p;
#pragma unroll
        for (int e = 0; e < 8; e++) oa[e] = fmaf(p, vd[e], oa[e]);
        kv0 = kv1;
        kv1 = kvn;
        j += 8;
    }

    if (wave != 0) {
#pragma unroll
        for (int e = 0; e < 8; e++) obuf[wave - 1][lane][e] = oa[e];
        sbuf[wave - 1][lane] = sum;
    }
    __syncthreads();
    if (wave == 0) {
#pragma unroll
        for (int w = 0; w < 7; w++) sum += sbuf[w][lane];
        float inv = 1.0f / sum;
        ushort8 ov;
#pragma unroll
        for (int e = 0; e < 8; e++) {
            float v = oa[e];
#pragma unroll
            for (int w = 0; w < 7; w++) v += obuf[w][lane][e];
            ov[e] = f2bf(v * inv);
        }
        *(ushort8*)(o + (size_t)qi * 512 + lane * 8) = ov;
    }
}

// ---------------------------------------------------------------- launch (11 dispatches)
extern "C" void kernel_launch(void* const* d_in, const int* in_sizes, int n_in,
                              void* d_out, int out_size, void* d_ws, size_t ws_size,
                              hipStream_t stream) {
    const float* nfeat = (const float*)d_in[0];
    const float* bo    = (const float*)d_in[11];
    const float* fc2_b = (const float*)d_in[17];

    const size_t ND = (size_t)NN * DD;
    const size_t SS = (size_t)DD * DD;
    float* x    = (float*)d_ws;                      // 8 MB
    u16*   xb   = (u16*)(x + ND);                    // 4 MB (bf16 shadow of x / nfeat)
    u16*   q    = xb + ND;                           // 4 MB (f16)
    u8*    kv8  = (u8*)(q + ND);                     // 4 MB (fp8 K|V interleaved)
    u16*   o    = (u16*)(kv8 + (size_t)NN * 1024);   // 4 MB
    u16*   m1   = o + ND;                            // 4 MB
    u16*   wc   = m1 + ND;                           // 12 MB
    float* bc2  = (float*)(wc + 12 * SS);            // [2][2048] bias+c2
    float* c1c  = bc2 + 2 * 2048;                    // [2][2048] c1
    float* st   = c1c + 2 * 2048;                    // 4 stats buffers x 8192
    int*   idx  = (int*)(st + 4 * 8192);             // 4 MB
    int*   cnt  = idx + (size_t)NN * CAP;

    SP sp;
    sp.w[0] = (const float*)d_in[4];  sp.bq = (const float*)d_in[5];
    sp.w[1] = (const float*)d_in[6];  sp.bk = (const float*)d_in[7];
    sp.w[2] = (const float*)d_in[8];  sp.bv = (const float*)d_in[9];
    sp.w[3] = (const float*)d_in[10];
    sp.w[4] = (const float*)d_in[14]; sp.fc1_b = (const float*)d_in[15];
    sp.w[5] = (const float*)d_in[16];
    sp.ln1_g = (const float*)d_in[2];  sp.ln1_b = (const float*)d_in[3];
    sp.ln2_g = (const float*)d_in[12]; sp.ln2_b = (const float*)d_in[13];
    sp.nfeat = nfeat; sp.mask = (const int*)d_in[1];

    setup_kernel<<<192 + NN + 1024, 256, 0, stream>>>(sp, wc, bc2, c1c, st, xb, idx, cnt);

    for (int l = 0; l < 2; l++) {
        size_t bOff = (size_t)l * DD;
        u16* wl = wc + (size_t)l * 6 * SS;
        const float* xin = (l == 0) ? nfeat : x;
        float* fc2_dst = (l == 1) ? (float*)d_out : x;
        float* st_ln1 = st + (l == 0 ? 0 : 2) * 8192;   // st0 (setup) / st2 (fc2 L0)
        float* st_ln2 = st + (l == 0 ? 1 : 3) * 8192;   // st1 (proj L0) / st3 (proj L1)

        // QKV (LN1 folded): reads raw-x bf16 shadow
        gemm_qkv<<<dim3(24, 32), 256, 0, stream>>>(xb, wl, bc2 + l * 2048, c1c + l * 2048,
                                                   st_ln1, q, kv8);
        sparse_attn<<<NN, 512, 0, stream>>>(q, kv8, idx, cnt, o);
        // proj: x = xin + o@Wo^T + bo;  writes xb shadow + LN2 stats
        gemm_fc<2, 0><<<dim3(8, 64), 256, 0, stream>>>(o, wl + 3 * SS, bo + bOff, nullptr,
                                                       nullptr, xin, x, nullptr, xb, st_ln2);
        // FC1 (LN2 folded): m1 = gelu(LN2(x)@W1^T + b1) from xb shadow
        gemm_fc<1, 1><<<dim3(8, 64), 256, 0, stream>>>(xb, wl + 4 * SS,
                                                       bc2 + l * 2048 + 1536,
                                                       c1c + l * 2048 + 1536,
                                                       st_ln2, nullptr, nullptr, m1,
                                                       nullptr, nullptr);
        // FC2: dst = x + m1@W2^T + b2;  layer0 also writes xb shadow + LN1(L1) stats
        gemm_fc<2, 0><<<dim3(8, 64), 256, 0, stream>>>(m1, wl + 5 * SS, fc2_b + bOff, nullptr,
                                                       nullptr, x, fc2_dst, nullptr,
                                                       (l == 0) ? xb : nullptr,
                                                       (l == 0) ? (st + 2 * 8192) : nullptr);
    }
}

// Round 14
// 263.341 us; speedup vs baseline: 1.0159x; 1.0159x over previous
//
#include <hip/hip_runtime.h>
#include <math.h>

#define NN 4096
#define DD 512
#define FF 512
#define CAP 256
#define SCALE 0.08838834764831845f

typedef unsigned short u16;
typedef unsigned char u8;
typedef unsigned int u32;
typedef __attribute__((ext_vector_type(8))) short short8;
typedef __attribute__((ext_vector_type(8))) unsigned short ushort8;
typedef __attribute__((ext_vector_type(4))) unsigned short ushort4v;
typedef __attribute__((ext_vector_type(4))) float floatx4;
typedef __attribute__((ext_vector_type(2))) float f32x2;
typedef _Float16 half8v __attribute__((ext_vector_type(8)));

__device__ __forceinline__ u16 f2bf(float f) {
    union { float f; unsigned int i; } x; x.f = f;
    unsigned int r = (x.i + 0x7FFFu + ((x.i >> 16) & 1u)) >> 16;
    return (u16)r;
}
__device__ __forceinline__ u16 f2h(float f) {
    _Float16 h = (_Float16)f;
    union { _Float16 h; u16 u; } x; x.h = h; return x.u;
}
// f32 -> fp8 e4m3 (RNE) via the f16 domain: e4m3 bits == f16 bits of (x/256) >> 7.
__device__ __forceinline__ u8 f2fp8(float f) {
    union { _Float16 h; u16 u; } x;
    x.h = (_Float16)(f * 0.00390625f);          // /256
    u16 h = x.u;
    h = h + 0x3F + ((h >> 7) & 1);              // RNE on the 7 dropped bits
    return (u8)(((h >> 8) & 0x80) | ((h >> 7) & 0x7f));
}
__device__ __forceinline__ float fp82f_sw(u8 b) {
    union { u16 u; _Float16 h; } x;
    x.u = (u16)(((u16)(b & 0x80) << 8) | ((u16)(b & 0x7f) << 7));
    return (float)x.h * 256.0f;
}
__device__ __forceinline__ void gld_lds16(const void* g, void* l) {
    __builtin_amdgcn_global_load_lds((const __attribute__((address_space(1))) void*)g,
                                     (__attribute__((address_space(3))) void*)l, 16, 0, 0);
}

// fast exact-gelu: A&S 7.1.26 erf approx, |eps_erf| <= 1.5e-7
__device__ __forceinline__ float gelu_fast(float val) {
    float z = fabsf(val) * 0.70710678118654752f;
    float tt = __builtin_amdgcn_rcpf(fmaf(0.3275911f, z, 1.0f));
    float p = fmaf(1.061405429f, tt, -1.453152027f);
    p = fmaf(p, tt, 1.421413741f);
    p = fmaf(p, tt, -0.284496736f);
    p = fmaf(p, tt, 0.254829592f);
    p = p * tt * __expf(-z * z);
    float er_ = 1.0f - p;
    float sgn = (val < 0.f) ? -er_ : er_;
    return val * 0.5f * (1.0f + sgn);
}

// ---------------------------------------------------------------- fused setup (R8-proven)
// [0,192): weight cast fp32->bf16 with LN-gamma fold; blocks 2,3 also zero st1..st3
// [192, 192+NN): mask -> idx  +  nfeat stats -> st0  +  nfeat -> xb (bf16), one row per block
// [192+NN, +1024): c1/c2 fold, one column per wave
struct SP {
    const float* w[6];
    const float* bq; const float* bk; const float* bv; const float* fc1_b;
    const float* ln1_g; const float* ln1_b; const float* ln2_g; const float* ln2_b;
    const float* nfeat; const int* mask;
};
__global__ void setup_kernel(SP sp, u16* __restrict__ wc, float* __restrict__ bc2,
                             float* __restrict__ c1c, float* __restrict__ st,
                             u16* __restrict__ xb, int* __restrict__ idx,
                             int* __restrict__ cnt) {
    const int bid = blockIdx.x;
    const int t = threadIdx.x;
    const int wave = t >> 6, lane = t & 63;
    if (bid < 192) {
        // ---- weight cast with gamma fold ----
        int region = bid >> 4;
        int layer = region / 6, mat = region - layer * 6;
        const float* src = sp.w[mat] + (size_t)layer * (DD * DD);
        u16* d = wc + (size_t)region * (DD * DD);
        int off = (bid & 15) * 16384 + t * 4;
        int k = (t * 4) & 511;
        float4 g4 = {1.f, 1.f, 1.f, 1.f};
        if (mat < 3)      g4 = *(const float4*)&sp.ln1_g[layer * DD + k];
        else if (mat == 4) g4 = *(const float4*)&sp.ln2_g[layer * DD + k];
#pragma unroll
        for (int i = 0; i < 16; i++) {
            int e = off + i * 1024;
            float4 f = *(const float4*)&src[e];
            ushort4v u;
            u.x = f2bf(f.x * g4.x); u.y = f2bf(f.y * g4.y);
            u.z = f2bf(f.z * g4.z); u.w = f2bf(f.w * g4.w);
            *(ushort4v*)&d[e] = u;
        }
        if (bid == 2 || bid == 3) {   // zero st1..st3 (atomic accumulators)
            float* z = st + 8192;
            int base = (bid - 2) * 256 + t;
#pragma unroll
            for (int i = 0; i < 48; i++) z[base + i * 512] = 0.0f;
        }
        return;
    }
    if (bid < 192 + NN) {
        int row = bid - 192;
        // ---- nfeat: stats + bf16 cast (2 elems/thread) ----
        __shared__ int c;
        __shared__ float ws[4][2];
        const float* xr = sp.nfeat + (size_t)row * DD;
        float2 v2 = *(const float2*)&xr[t * 2];
        float s1 = v2.x + v2.y, s2 = v2.x * v2.x + v2.y * v2.y;
#pragma unroll
        for (int off = 32; off; off >>= 1) { s1 += __shfl_xor(s1, off); s2 += __shfl_xor(s2, off); }
        if (lane == 0) { ws[wave][0] = s1; ws[wave][1] = s2; }
        u32 pack = (u32)f2bf(v2.x) | ((u32)f2bf(v2.y) << 16);
        ((u32*)xb)[row * 256 + t] = pack;
        if (t == 0) c = 0;
        __syncthreads();
        if (t == 0) {
            float S1 = ws[0][0] + ws[1][0] + ws[2][0] + ws[3][0];
            float S2 = ws[0][1] + ws[1][1] + ws[2][1] + ws[3][1];
            st[row * 2] = S1; st[row * 2 + 1] = S2;
        }
        // ---- mask -> idx (block-per-row, LDS atomic; R0-proven shape) ----
        const int4* mrow = (const int4*)(sp.mask + (size_t)row * NN);
        for (int j4 = t; j4 < NN / 4; j4 += blockDim.x) {
            int4 m4 = mrow[j4];
            int base = j4 * 4;
            if (m4.x == 0) idx[row * CAP + atomicAdd(&c, 1)] = base;
            if (m4.y == 0) idx[row * CAP + atomicAdd(&c, 1)] = base + 1;
            if (m4.z == 0) idx[row * CAP + atomicAdd(&c, 1)] = base + 2;
            if (m4.w == 0) idx[row * CAP + atomicAdd(&c, 1)] = base + 3;
        }
        __syncthreads();
        if (t == 0) cnt[row] = (c < CAP) ? c : CAP;
        return;
    }
    // ---- c1/c2 fold: one column per wave (R8-proven) ----
    {
        int colg = (bid - (192 + NN)) * 4 + wave;   // 0..4095
        int l = colg >> 11, j = colg & 2047;
        const float* W; const float* g; const float* b; float bias;
        if (j < 1536) {
            int mat = j >> 9, col = j & 511;
            W = sp.w[mat] + (size_t)l * DD * DD + (size_t)col * DD;
            g = sp.ln1_g + l * DD; b = sp.ln1_b + l * DD;
            bias = (mat == 0 ? sp.bq : mat == 1 ? sp.bk : sp.bv)[l * DD + col];
        } else {
            int col = j - 1536;
            W = sp.w[4] + (size_t)l * DD * DD + (size_t)col * DD;
            g = sp.ln2_g + l * DD; b = sp.ln2_b + l * DD;
            bias = sp.fc1_b[l * DD + col];
        }
        int k = lane * 8;
        float4 w0 = *(const float4*)&W[k];
        float4 w1 = *(const float4*)&W[k + 4];
        float4 g0 = *(const float4*)&g[k];
        float4 g1 = *(const float4*)&g[k + 4];
        float4 b0 = *(const float4*)&b[k];
        float4 b1 = *(const float4*)&b[k + 4];
        float c1 = w0.x * g0.x + w0.y * g0.y + w0.z * g0.z + w0.w * g0.w
                 + w1.x * g1.x + w1.y * g1.y + w1.z * g1.z + w1.w * g1.w;
        float c2 = w0.x * b0.x + w0.y * b0.y + w0.z * b0.z + w0.w * b0.w
                 + w1.x * b1.x + w1.y * b1.y + w1.z * b1.z + w1.w * b1.w;
#pragma unroll
        for (int off = 32; off; off >>= 1) { c1 += __shfl_xor(c1, off); c2 += __shfl_xor(c2, off); }
        if (lane == 0) { c1c[colg] = c1; bc2[colg] = bias + c2; }
    }
}

// LDS row-rotation swizzle (R12-proven): LDS(row, pos) holds global chunk (pos - row) & 7.

// ---------------------------------------------------------------- 64x64 FC GEMM (R0-proven body)
// XCD-aware tile swizzle (T1, R11-proven). k0=0 stage issued FIRST (R14: overlap first-tile
// latency with rin/stats preloads).
// LNF=1: A is raw-x bf16, B is gamma-folded; epilogue applies val = r*acc - r*mu*c1 + bc2
// MODE 1: gelu -> bf16 outB; MODE 2: resOut = resIn + val (+ optional xb shadow + row stats)
template <int MODE, int LNF>
__launch_bounds__(256)
__global__ void gemm_fc(const u16* __restrict__ A, const u16* __restrict__ B,
                        const float* __restrict__ bias, const float* __restrict__ c1,
                        const float* __restrict__ stats, const float* __restrict__ resIn,
                        float* __restrict__ resOut, u16* __restrict__ outB,
                        u16* __restrict__ xbOut, float* __restrict__ statsOut) {
    __shared__ __align__(16) u8 smem[16384];
    u16* As = (u16*)smem;
    u16* Bs = (u16*)(smem + 8192);
    const int lin = blockIdx.x + blockIdx.y * 8;        // 512 tiles, round-robin over 8 XCDs
    const int v = (lin & 7) * 64 + (lin >> 3);          // bijective: XCD-contiguous tile bands
    const int m0 = (v >> 3) * 64, n0 = (v & 7) * 64;
    const int t = threadIdx.x;
    const int wave = t >> 6, lane = t & 63;
    const int wm = (wave & 1) * 32, wn = (wave >> 1) * 32;
    const int sr = t >> 3;
    const int sc = ((((t & 7) - (t >> 3)) & 7)) * 8;
    const int fr = lane & 15, g0 = lane >> 4;
    const int er = (lane >> 4) * 4, ec = lane & 15;

    floatx4 acc[2][2] = {};
    const u16* ag0 = A + (size_t)(m0 + sr) * 512 + sc;
    const u16* ag1 = A + (size_t)(m0 + 32 + sr) * 512 + sc;
    const u16* bg0 = B + (size_t)(n0 + sr) * 512 + sc;
    const u16* bg1 = B + (size_t)(n0 + 32 + sr) * 512 + sc;

    // issue first K-tile stage immediately (latency overlaps the preloads below)
    gld_lds16(ag0, As + t * 8);
    gld_lds16(ag1, As + 2048 + t * 8);
    gld_lds16(bg0, Bs + t * 8);
    gld_lds16(bg1, Bs + 2048 + t * 8);

    float rin[16];
    if (MODE == 2) {
#pragma unroll
        for (int i = 0; i < 2; i++)
#pragma unroll
            for (int j = 0; j < 2; j++)
#pragma unroll
                for (int r = 0; r < 4; r++)
                    rin[(i * 2 + j) * 4 + r] =
                        resIn[(size_t)(m0 + wm + 16 * i + er + r) * 512 + (n0 + wn + 16 * j + ec)];
    }
    // LNF: per-row affine (a = r, b = -r*mu) for this thread's 8 rows
    float ar[2][4], br[2][4];
    if (LNF) {
#pragma unroll
        for (int i = 0; i < 2; i++) {
            int r0 = m0 + wm + 16 * i + er;
#pragma unroll
            for (int r = 0; r < 4; r++) {
                f32x2 s = *(const f32x2*)&stats[(r0 + r) * 2];
                float m = s.x * (1.0f / DD);
                float rr = rsqrtf(s.y * (1.0f / DD) - m * m + 1e-5f);
                ar[i][r] = rr; br[i][r] = -rr * m;
            }
        }
    }

    for (int k0 = 0; k0 < 512; k0 += 64) {
        if (k0) {
            __syncthreads();
            gld_lds16(ag0 + k0, As + t * 8);
            gld_lds16(ag1 + k0, As + 2048 + t * 8);
            gld_lds16(bg0 + k0, Bs + t * 8);
            gld_lds16(bg1 + k0, Bs + 2048 + t * 8);
        }
        __syncthreads();
#pragma unroll
        for (int h = 0; h < 2; h++) {
            const int fo = (((h << 2) + g0 + fr) & 7) << 3;
            short8 af[2], bf[2];
#pragma unroll
            for (int i = 0; i < 2; i++) af[i] = *(const short8*)&As[(wm + 16 * i + fr) * 64 + fo];
#pragma unroll
            for (int j = 0; j < 2; j++) bf[j] = *(const short8*)&Bs[(wn + 16 * j + fr) * 64 + fo];
#pragma unroll
            for (int i = 0; i < 2; i++)
#pragma unroll
                for (int j = 0; j < 2; j++)
                    acc[i][j] = __builtin_amdgcn_mfma_f32_16x16x32_bf16(af[i], bf[j], acc[i][j], 0, 0, 0);
        }
    }

    float outv[16];
#pragma unroll
    for (int j = 0; j < 2; j++) {
        int col = n0 + wn + 16 * j + ec;
        float bsv = bias[col];
        float c1v = LNF ? c1[col] : 0.f;
#pragma unroll
        for (int i = 0; i < 2; i++) {
#pragma unroll
            for (int r = 0; r < 4; r++) {
                int row = m0 + wm + 16 * i + er + r;
                float val;
                if (LNF) val = fmaf(ar[i][r], acc[i][j][r], fmaf(br[i][r], c1v, bsv));
                else     val = acc[i][j][r] + bsv;
                if (MODE == 1) {
                    outB[(size_t)row * 512 + col] = f2bf(gelu_fast(val));
                } else {
                    float ov = rin[(i * 2 + j) * 4 + r] + val;
                    outv[(i * 2 + j) * 4 + r] = ov;
                    resOut[(size_t)row * 512 + col] = ov;
                    if (xbOut) xbOut[(size_t)row * 512 + col] = f2bf(ov);
                }
            }
        }
    }

    if (MODE == 2 && statsOut) {   // row (sum, sumsq) accumulation for the next LN (R2-proven)
        __syncthreads();
        float* Ls = (float*)smem;              // 64x64 f32 = 16 KB
#pragma unroll
        for (int i = 0; i < 2; i++)
#pragma unroll
            for (int j = 0; j < 2; j++)
#pragma unroll
                for (int r = 0; r < 4; r++)
                    Ls[(wm + 16 * i + er + r) * 64 + (wn + 16 * j + ec)] = outv[(i * 2 + j) * 4 + r];
        __syncthreads();
        if (t < 64) {
            float s1 = 0.f, s2 = 0.f;
            for (int c0 = 0; c0 < 64; c0++) {
                int cc = (c0 + t) & 63;        // stagger: 2-way conflict max (free)
                float v2 = Ls[t * 64 + cc];
                s1 += v2; s2 += v2 * v2;
            }
            atomicAdd(&statsOut[(size_t)(m0 + t) * 2], s1);
            atomicAdd(&statsOut[(size_t)(m0 + t) * 2 + 1], s2);
        }
    }
}

// ---------------------------------------------------------------- 128x64 QKV GEMM (R0-proven body)
// XCD-aware tile swizzle (T1). LN folded; epilogue applies per-row affine. k0=0 staged first.
// Q -> f16 q[N,512]; K/V -> fp8 interleaved kv8[N][64 grp][K8|V8]
__launch_bounds__(256)
__global__ void gemm_qkv(const u16* __restrict__ A, const u16* __restrict__ B,
                         const float* __restrict__ bias, const float* __restrict__ c1,
                         const float* __restrict__ stats, u16* __restrict__ qOut,
                         u8* __restrict__ kv8) {
    __shared__ u16 As[128 * 64];   // 16 KB
    __shared__ u16 Bs[64 * 64];    // 8 KB
    const int lin = blockIdx.x + blockIdx.y * 24;       // 768 tiles
    const int v = (lin & 7) * 96 + (lin >> 3);          // bijective XCD bands
    const int rb = v / 24, cb = v - rb * 24;
    const int m0 = rb * 128, n0 = cb * 64;
    const int t = threadIdx.x;
    const int wave = t >> 6, lane = t & 63;
    const int wm = (wave & 1) * 64, wn = (wave >> 1) * 32;
    const int sr = t >> 3;
    const int sc = ((((t & 7) - (t >> 3)) & 7)) * 8;
    const int fr = lane & 15, g0 = lane >> 4;
    const int er = (lane >> 4) * 4, ec = lane & 15;

    floatx4 acc[4][2] = {};
    const u16* agp[4];
    u16* asp[4];
#pragma unroll
    for (int u = 0; u < 4; u++) {
        agp[u] = A + (size_t)(m0 + 32 * u + sr) * DD + sc;
        asp[u] = As + u * (32 * 64) + t * 8;
    }
    const u16* bg0 = B + (size_t)(n0 + sr) * DD + sc;
    const u16* bg1 = B + (size_t)(n0 + 32 + sr) * DD + sc;

    // issue first K-tile stage immediately (latency overlaps the stats loads below)
#pragma unroll
    for (int u = 0; u < 4; u++) gld_lds16(agp[u], asp[u]);
    gld_lds16(bg0, Bs + t * 8);
    gld_lds16(bg1, Bs + 2048 + t * 8);

    float ar[4][4], br[4][4];
#pragma unroll
    for (int i = 0; i < 4; i++) {
        int r0 = m0 + wm + 16 * i + er;
#pragma unroll
        for (int r = 0; r < 4; r++) {
            f32x2 s = *(const f32x2*)&stats[(r0 + r) * 2];
            float m = s.x * (1.0f / DD);
            float rr = rsqrtf(s.y * (1.0f / DD) - m * m + 1e-5f);
            ar[i][r] = rr; br[i][r] = -rr * m;
        }
    }

    for (int k0 = 0; k0 < DD; k0 += 64) {
        if (k0) {
            __syncthreads();
#pragma unroll
            for (int u = 0; u < 4; u++) gld_lds16(agp[u] + k0, asp[u]);
            gld_lds16(bg0 + k0, Bs + t * 8);
            gld_lds16(bg1 + k0, Bs + 2048 + t * 8);
        }
        __syncthreads();
#pragma unroll
        for (int h = 0; h < 2; h++) {
            const int fo = (((h << 2) + g0 + fr) & 7) << 3;
            short8 af[4], bf[2];
#pragma unroll
            for (int i = 0; i < 4; i++) af[i] = *(const short8*)&As[(wm + 16 * i + fr) * 64 + fo];
#pragma unroll
            for (int j = 0; j < 2; j++) bf[j] = *(const short8*)&Bs[(wn + 16 * j + fr) * 64 + fo];
#pragma unroll
            for (int i = 0; i < 4; i++)
#pragma unroll
                for (int j = 0; j < 2; j++)
                    acc[i][j] = __builtin_amdgcn_mfma_f32_16x16x32_bf16(af[i], bf[j], acc[i][j], 0, 0, 0);
        }
    }

#pragma unroll
    for (int j = 0; j < 2; j++) {
        int col = n0 + wn + 16 * j + ec;
        float bsv = bias[col];
        float c1v = c1[col];
#pragma unroll
        for (int i = 0; i < 4; i++) {
#pragma unroll
            for (int r = 0; r < 4; r++) {
                int row = m0 + wm + 16 * i + er + r;
                float val = fmaf(ar[i][r], acc[i][j][r], fmaf(br[i][r], c1v, bsv));
                if (cb < 8) {                         // Q -> f16
                    qOut[(size_t)row * 512 + col] = f2h(val);
                } else if (cb < 16) {                 // K -> fp8, group-interleaved
                    int cc = col - 512;
                    kv8[(size_t)row * 1024 + 16 * (cc >> 3) + (cc & 7)] = f2fp8(val);
                } else {                              // V -> fp8
                    int cc = col - 1024;
                    kv8[(size_t)row * 1024 + 16 * (cc >> 3) + 8 + (cc & 7)] = f2fp8(val);
                }
            }
        }
    }
}

// ---------------------------------------------------------------- sparse attention (R12-proven):
// 4 waves/query, 2 queries/block (8 waves); fp8 KV, f16 Q; depth-3 prefetch (R14);
// 3-partial LDS combine.
__launch_bounds__(512)
__global__ void sparse_attn(const u16* __restrict__ q, const u8* __restrict__ kv8,
                            const int* __restrict__ idx, const int* __restrict__ cnt,
                            u16* __restrict__ o) {
    int t = threadIdx.x;
    int wave = t >> 6, lane = t & 63;
    int qslot = wave >> 2, quarter = wave & 3;
    int qi = blockIdx.x * 2 + qslot;
    __shared__ float obuf[3][2][64][8];   // 12 KB: partials from quarters 1..3
    __shared__ float sbuf[3][2][64];      // 1.5 KB
    __shared__ int sidx[2][CAP];          // 2 KB

    int c = cnt[qi];
    {
        int qs2 = t >> 8, tl = t & 255;
        int qiL = blockIdx.x * 2 + qs2;
        int cL = cnt[qiL];
        for (int j = tl; j < cL; j += 256) sidx[qs2][j] = idx[qiL * CAP + j];
    }

    half8v qv = *(const half8v*)(q + (size_t)qi * 512 + lane * 8);
    float qf[8];
#pragma unroll
    for (int e = 0; e < 8; e++) qf[e] = (float)qv[e];
    __syncthreads();

    float sum = 0.f, oa[8] = {};
    int j = quarter;
    int4 kv0, kv1, kv2;
    {
        int k0i = (j < c) ? sidx[qslot][j] : 0;
        int k1i = (j + 4 < c) ? sidx[qslot][j + 4] : 0;
        int k2i = (j + 8 < c) ? sidx[qslot][j + 8] : 0;
        kv0 = *(const int4*)(kv8 + (size_t)k0i * 1024 + lane * 16);
        kv1 = *(const int4*)(kv8 + (size_t)k1i * 1024 + lane * 16);
        kv2 = *(const int4*)(kv8 + (size_t)k2i * 1024 + lane * 16);
    }
    while (j < c) {
        int4 kvn;
        {
            int kjn = (j + 12 < c) ? sidx[qslot][j + 12] : 0;
            kvn = *(const int4*)(kv8 + (size_t)kjn * 1024 + lane * 16);
        }
        float kd[8], vd[8];
#if __has_builtin(__builtin_amdgcn_cvt_pk_f32_fp8)
        {
            f32x2 p0 = __builtin_amdgcn_cvt_pk_f32_fp8(kv0.x, false);
            f32x2 p1 = __builtin_amdgcn_cvt_pk_f32_fp8(kv0.x, true);
            f32x2 p2 = __builtin_amdgcn_cvt_pk_f32_fp8(kv0.y, false);
            f32x2 p3 = __builtin_amdgcn_cvt_pk_f32_fp8(kv0.y, true);
            kd[0] = p0.x; kd[1] = p0.y; kd[2] = p1.x; kd[3] = p1.y;
            kd[4] = p2.x; kd[5] = p2.y; kd[6] = p3.x; kd[7] = p3.y;
            f32x2 p4 = __builtin_amdgcn_cvt_pk_f32_fp8(kv0.z, false);
            f32x2 p5 = __builtin_amdgcn_cvt_pk_f32_fp8(kv0.z, true);
            f32x2 p6 = __builtin_amdgcn_cvt_pk_f32_fp8(kv0.w, false);
            f32x2 p7 = __builtin_amdgcn_cvt_pk_f32_fp8(kv0.w, true);
            vd[0] = p4.x; vd[1] = p4.y; vd[2] = p5.x; vd[3] = p5.y;
            vd[4] = p6.x; vd[5] = p6.y; vd[6] = p7.x; vd[7] = p7.y;
        }
#else
        {
            const u8* bp = (const u8*)&kv0;
#pragma unroll
            for (int e = 0; e < 8; e++) { kd[e] = fp82f_sw(bp[e]); vd[e] = fp82f_sw(bp[8 + e]); }
        }
#endif
        float d = 0.f;
#pragma unroll
        for (int e = 0; e < 8; e++) d = fmaf(qf[e], kd[e], d);
        d += __shfl_xor(d, 1);
        d += __shfl_xor(d, 2);
        d += __shfl_xor(d, 4);
        d += __shfl_xor(d, 8);
        float p = __expf(d * SCALE);
        sum += p;
#pragma unroll
        for (int e = 0; e < 8; e++) oa[e] = fmaf(p, vd[e], oa[e]);
        kv0 = kv1;
        kv1 = kv2;
        kv2 = kvn;
        j += 4;
    }

    if (quarter != 0) {
#pragma unroll
        for (int e = 0; e < 8; e++) obuf[quarter - 1][qslot][lane][e] = oa[e];
        sbuf[quarter - 1][qslot][lane] = sum;
    }
    __syncthreads();
    if (quarter == 0) {
        sum += sbuf[0][qslot][lane] + sbuf[1][qslot][lane] + sbuf[2][qslot][lane];
        float inv = 1.0f / sum;
        ushort8 ov;
#pragma unroll
        for (int e = 0; e < 8; e++) {
            float v = oa[e] + obuf[0][qslot][lane][e] + obuf[1][qslot][lane][e]
                    + obuf[2][qslot][lane][e];
            ov[e] = f2bf(v * inv);
        }
        *(ushort8*)(o + (size_t)qi * 512 + lane * 8) = ov;
    }
}

// ---------------------------------------------------------------- launch (11 dispatches)
extern "C" void kernel_launch(void* const* d_in, const int* in_sizes, int n_in,
                              void* d_out, int out_size, void* d_ws, size_t ws_size,
                              hipStream_t stream) {
    const float* nfeat = (const float*)d_in[0];
    const float* bo    = (const float*)d_in[11];
    const float* fc2_b = (const float*)d_in[17];

    const size_t ND = (size_t)NN * DD;
    const size_t SS = (size_t)DD * DD;
    float* x    = (float*)d_ws;                      // 8 MB
    u16*   xb   = (u16*)(x + ND);                    // 4 MB (bf16 shadow of x / nfeat)
    u16*   q    = xb + ND;                           // 4 MB (f16)
    u8*    kv8  = (u8*)(q + ND);                     // 4 MB (fp8 K|V interleaved)
    u16*   o    = (u16*)(kv8 + (size_t)NN * 1024);   // 4 MB
    u16*   m1   = o + ND;                            // 4 MB
    u16*   wc   = m1 + ND;                           // 12 MB
    float* bc2  = (float*)(wc + 12 * SS);            // [2][2048] bias+c2
    float* c1c  = bc2 + 2 * 2048;                    // [2][2048] c1
    float* st   = c1c + 2 * 2048;                    // 4 stats buffers x 8192
    int*   idx  = (int*)(st + 4 * 8192);             // 4 MB
    int*   cnt  = idx + (size_t)NN * CAP;

    SP sp;
    sp.w[0] = (const float*)d_in[4];  sp.bq = (const float*)d_in[5];
    sp.w[1] = (const float*)d_in[6];  sp.bk = (const float*)d_in[7];
    sp.w[2] = (const float*)d_in[8];  sp.bv = (const float*)d_in[9];
    sp.w[3] = (const float*)d_in[10];
    sp.w[4] = (const float*)d_in[14]; sp.fc1_b = (const float*)d_in[15];
    sp.w[5] = (const float*)d_in[16];
    sp.ln1_g = (const float*)d_in[2];  sp.ln1_b = (const float*)d_in[3];
    sp.ln2_g = (const float*)d_in[12]; sp.ln2_b = (const float*)d_in[13];
    sp.nfeat = nfeat; sp.mask = (const int*)d_in[1];

    setup_kernel<<<192 + NN + 1024, 256, 0, stream>>>(sp, wc, bc2, c1c, st, xb, idx, cnt);

    for (int l = 0; l < 2; l++) {
        size_t bOff = (size_t)l * DD;
        u16* wl = wc + (size_t)l * 6 * SS;
        const float* xin = (l == 0) ? nfeat : x;
        float* fc2_dst = (l == 1) ? (float*)d_out : x;
        float* st_ln1 = st + (l == 0 ? 0 : 2) * 8192;   // st0 (setup) / st2 (fc2 L0)
        float* st_ln2 = st + (l == 0 ? 1 : 3) * 8192;   // st1 (proj L0) / st3 (proj L1)

        // QKV (LN1 folded): reads raw-x bf16 shadow
        gemm_qkv<<<dim3(24, 32), 256, 0, stream>>>(xb, wl, bc2 + l * 2048, c1c + l * 2048,
                                                   st_ln1, q, kv8);
        sparse_attn<<<NN / 2, 512, 0, stream>>>(q, kv8, idx, cnt, o);
        // proj: x = xin + o@Wo^T + bo;  writes xb shadow + LN2 stats
        gemm_fc<2, 0><<<dim3(8, 64), 256, 0, stream>>>(o, wl + 3 * SS, bo + bOff, nullptr,
                                                       nullptr, xin, x, nullptr, xb, st_ln2);
        // FC1 (LN2 folded): m1 = gelu(LN2(x)@W1^T + b1) from xb shadow
        gemm_fc<1, 1><<<dim3(8, 64), 256, 0, stream>>>(xb, wl + 4 * SS,
                                                       bc2 + l * 2048 + 1536,
                                                       c1c + l * 2048 + 1536,
                                                       st_ln2, nullptr, nullptr, m1,
                                                       nullptr, nullptr);
        // FC2: dst = x + m1@W2^T + b2;  layer0 also writes xb shadow + LN1(L1) stats
        gemm_fc<2, 0><<<dim3(8, 64), 256, 0, stream>>>(m1, wl + 5 * SS, fc2_b + bOff, nullptr,
                                                       nullptr, x, fc2_dst, nullptr,
                                                       (l == 0) ? xb : nullptr,
                                                       (l == 0) ? (st + 2 * 8192) : nullptr);
    }
}